// Round 7
// baseline (75.712 us; speedup 1.0000x reference)
//
#include <hip/hip_runtime.h>

// EmbeddingGrad_48137993454109
// Reference: out[b,l,d] = W[d, idx[b,l]] + bias[d]
//   idx : int32 [1024,50]          (in[0], 51200 elems)
//   W   : f32   [128, 8192]        (in[1], 1048576 elems)
//   b   : f32   [128]              (in[2])
//   out : f32   [1024,50,128]      (6553600 elems)
//
// R4: passed, absmax 0, dur 75.7us. Top-5 dispatches all harness ws-poison
// fills (268MB @ ~6TB/s, 44-46us); our kernels < 44us each.
// R5: compile fail — __builtin_nontemporal_store rejects HIP_vector_type.
// R6: same plan, native ext_vector float4 (f32x4). K2 theory: latency +
// L2-thrash bound; nt-stores keep 26MB write stream out of L2 (Wt = 4MB =
// per-XCD L2), 4-way ILP amortizes idx->gather dependent chain.

#define VOCAB 8192
#define DIM   128
#define NROWS (1024 * 50)            // 51200 output rows
#define TOTAL4 (NROWS * (DIM / 4))   // 1,638,400 float4s

typedef float f32x4 __attribute__((ext_vector_type(4)));

__global__ __launch_bounds__(256)
void transpose_bias_kernel(const float* __restrict__ W,
                           const float* __restrict__ bias,
                           float* __restrict__ Wt) {
    // 64x64 tile; +1 pad keeps LDS reads conflict-free
    __shared__ float tile[64][65];
    const int v0 = blockIdx.x * 64;   // vocab offset
    const int d0 = blockIdx.y * 64;   // dim offset (0 or 64)
    const int tx = threadIdx.x & 63;
    const int ty = threadIdx.x >> 6;  // 0..3

    // Coalesced read: W[d0+d][v0+tx], consecutive lanes -> consecutive v
#pragma unroll
    for (int i = 0; i < 16; ++i) {
        const int d = ty + 4 * i;
        tile[d][tx] = W[(size_t)(d0 + d) * VOCAB + (v0 + tx)];
    }
    __syncthreads();

    const float bv = bias[d0 + tx];
    // Coalesced write: Wt[v0+v][d0+tx], consecutive lanes -> consecutive d
#pragma unroll
    for (int i = 0; i < 16; ++i) {
        const int v = ty + 4 * i;
        Wt[(size_t)(v0 + v) * DIM + (d0 + tx)] = tile[tx][v] + bv;
    }
}

__global__ __launch_bounds__(256)
void gather_rows_kernel(const int* __restrict__ idx,
                        const f32x4* __restrict__ Wt4,
                        f32x4* __restrict__ out4) {
    // 4 float4s per thread at TOTAL4/4 stride: 4 independent idx loads issue
    // together, then 4 gathers, then 4 nt-stores -> latency amortized 4x.
    const int t0 = blockIdx.x * 256 + threadIdx.x;
    const int stride = TOTAL4 / 4;            // 409,600

    int v[4];
#pragma unroll
    for (int i = 0; i < 4; ++i) {
        const int t = t0 + i * stride;
        v[i] = idx[t >> 5];                   // broadcast within 32-lane group
    }
    f32x4 w[4];
#pragma unroll
    for (int i = 0; i < 4; ++i) {
        const int t = t0 + i * stride;
        w[i] = Wt4[(size_t)v[i] * 32 + (t & 31)];
    }
#pragma unroll
    for (int i = 0; i < 4; ++i) {
        const int t = t0 + i * stride;
        // nontemporal: keep the 26MB write stream from evicting Wt in L2
        __builtin_nontemporal_store(w[i], &out4[t]);
    }
}

extern "C" void kernel_launch(void* const* d_in, const int* in_sizes, int n_in,
                              void* d_out, int out_size, void* d_ws, size_t ws_size,
                              hipStream_t stream) {
    const int*   idx  = (const int*)d_in[0];
    const float* W    = (const float*)d_in[1];
    const float* bias = (const float*)d_in[2];
    float*       out  = (float*)d_out;
    float*       Wt   = (float*)d_ws;   // 8192*128*4 = 4 MB scratch

    dim3 tgrid(VOCAB / 64, DIM / 64);   // (128, 2)
    transpose_bias_kernel<<<tgrid, 256, 0, stream>>>(W, bias, Wt);

    gather_rows_kernel<<<TOTAL4 / (256 * 4), 256, 0, stream>>>(  // 1600 blocks
        idx, (const f32x4*)Wt, (f32x4*)out);
}

// Round 8
// 75.041 us; speedup vs baseline: 1.0089x; 1.0089x over previous
//
#include <hip/hip_runtime.h>

// EmbeddingGrad_48137993454109
// Reference: out[b,l,d] = W[d, idx[b,l]] + bias[d]
//   idx : int32 [1024,50], W : f32 [128,8192], b : f32 [128]
//   out : f32 [1024,50,128]
//
// R4: K1+K2(simple)      -> 75.65us, absmax 0
// R7: K1+K2(ILP+nt)      -> 75.71us  (identical to 0.08%!)
//   => timed window has a big fixed component (harness re-poison: 268MB ws
//      fill ~45us + 26MB out fill + restores + ~dozens of tiny dispatches).
//      K2 is NOT the dominant kernel term.
// R8 experiment: attack K1 (was 256 blocks = 1 block/CU = 1 wave/SIMD,
// latency-starved). 64v x 32d tiles -> 512 blocks, nt-loads for read-once W.
// K2 kept identical to R7. Predict 75.7 -> ~65-70us if K1 was ~10us;
// unchanged => harness floor dominates, declare structural ceiling.

#define VOCAB 8192
#define DIM   128
#define NROWS (1024 * 50)            // 51200 output rows
#define TOTAL4 (NROWS * (DIM / 4))   // 1,638,400 float4s

typedef float f32x4 __attribute__((ext_vector_type(4)));

__global__ __launch_bounds__(256)
void transpose_bias_kernel(const float* __restrict__ W,
                           const float* __restrict__ bias,
                           float* __restrict__ Wt) {
    // 64(v) x 32(d) tile, 512 blocks total (2 blocks/CU) for latency hiding
    __shared__ float tile[32][65];    // [d][v], stride 65 -> conflict-free
    const int v0 = blockIdx.x * 64;
    const int d0 = blockIdx.y * 32;
    const int tx = threadIdx.x & 63;  // v within tile
    const int ty = threadIdx.x >> 6;  // 0..3

    // Coalesced read: wave reads W[d0+d][v0 .. v0+63] = 256B contiguous.
    // nt-load: W is read exactly once, keep it out of L2 (Wt wants L2).
#pragma unroll
    for (int i = 0; i < 8; ++i) {
        const int d = ty + 4 * i;     // 0..31
        tile[d][tx] =
            __builtin_nontemporal_load(&W[(size_t)(d0 + d) * VOCAB + (v0 + tx)]);
    }
    __syncthreads();

    const int dd = threadIdx.x & 31;  // d within tile
    const int vv = threadIdx.x >> 5;  // 0..7
    const float bv = bias[d0 + dd];
    // Write: 32 consecutive d per half-wave = 128B contiguous segments.
    // LDS read tile[dd][v]: addr stride 65 floats across lanes -> bank = dd
    // (conflict-free).
#pragma unroll
    for (int i = 0; i < 8; ++i) {
        const int v = vv + 8 * i;     // 0..63
        Wt[(size_t)(v0 + v) * DIM + (d0 + dd)] = tile[dd][v] + bv;
    }
}

__global__ __launch_bounds__(256)
void gather_rows_kernel(const int* __restrict__ idx,
                        const f32x4* __restrict__ Wt4,
                        f32x4* __restrict__ out4) {
    // 4 float4s per thread at TOTAL4/4 stride: 4 independent idx loads issue
    // together, then 4 gathers, then 4 nt-stores -> latency amortized 4x.
    const int t0 = blockIdx.x * 256 + threadIdx.x;
    const int stride = TOTAL4 / 4;            // 409,600

    int v[4];
#pragma unroll
    for (int i = 0; i < 4; ++i) {
        const int t = t0 + i * stride;
        v[i] = idx[t >> 5];                   // broadcast within 32-lane group
    }
    f32x4 w[4];
#pragma unroll
    for (int i = 0; i < 4; ++i) {
        const int t = t0 + i * stride;
        w[i] = Wt4[(size_t)v[i] * 32 + (t & 31)];
    }
#pragma unroll
    for (int i = 0; i < 4; ++i) {
        const int t = t0 + i * stride;
        // nontemporal: keep the 26MB write stream from evicting Wt in L2
        __builtin_nontemporal_store(w[i], &out4[t]);
    }
}

extern "C" void kernel_launch(void* const* d_in, const int* in_sizes, int n_in,
                              void* d_out, int out_size, void* d_ws, size_t ws_size,
                              hipStream_t stream) {
    const int*   idx  = (const int*)d_in[0];
    const float* W    = (const float*)d_in[1];
    const float* bias = (const float*)d_in[2];
    float*       out  = (float*)d_out;
    float*       Wt   = (float*)d_ws;   // 8192*128*4 = 4 MB scratch

    dim3 tgrid(VOCAB / 64, DIM / 32);   // (128, 4) = 512 blocks
    transpose_bias_kernel<<<tgrid, 256, 0, stream>>>(W, bias, Wt);

    gather_rows_kernel<<<TOTAL4 / (256 * 4), 256, 0, stream>>>(  // 1600 blocks
        idx, (const f32x4*)Wt, (f32x4*)out);
}